// Round 8
// baseline (474.700 us; speedup 1.0000x reference)
//
#include <hip/hip_runtime.h>

#define T_LEN 1024
#define M_DIM 128
#define B_NUM 64

typedef _Float16 h2 __attribute__((ext_vector_type(2)));

#if __has_builtin(__builtin_amdgcn_fdot2)
#define DOT2(a, b, c) __builtin_amdgcn_fdot2((a), (b), (c), false)
#else
__device__ __forceinline__ float DOT2(h2 a, h2 b, float c) {
  return fmaf((float)a.x, (float)b.x, fmaf((float)a.y, (float)b.y, c));
}
#endif

// DPP lane-move (VALU pipe, no DS ops). bound_ctrl=true (0 on invalid).
template<int CTRL>
__device__ __forceinline__ float dppmov(float x) {
  int y = __builtin_amdgcn_update_dpp(0, __float_as_int(x), CTRL, 0xf, 0xf, true);
  return __int_as_float(y);
}

// One block (256 thr, 4 waves) per batch. lane = (jl = lane&31, half = lane>>5);
// j = wid*32 + jl (lane owns ONE output state, duplicated across halves).
// u stored in LDS as packed f16 pairs (pair m = states 2m,2m+1); half h reads
// its 32 pairs as 8 broadcast ds_read_b128 (half1 block at dword 36 so the two
// addresses per read hit disjoint bank quads -> conflict-free). W as f16 pairs
// in 32 VGPRs. 32 v_dot2_f32_f16 -> f32, one shfl_xor(32) combines halves.
// Renorm: LAG-1 (lag-2 resonates: m_t = m_{t-1}-m_{t-2}+c has unit-circle
// roots -> f16 overflow -> NaN, round-7 failure). Max-tree over un_t runs as
// a 5-DPP VALU chain (xor1,xor2,half_mirror,mirror,row_bcast15; lane16
// writes), parity-buffered red[2][4], consumed next step. 2^-8 headroom per
// step (tracked in C) bounds stored max at ~4050 < f16 max. sY hoisted.
__global__ __launch_bounds__(256, 1) void crf_fwd(
    const float* __restrict__ P, const float* __restrict__ A,
    const int* __restrict__ Y, const int* __restrict__ L,
    float* __restrict__ out)
{
  const int b    = blockIdx.x;
  const int tid  = threadIdx.x;
  const int lane = tid & 63;
  const int wid  = tid >> 6;     // 0..3
  const int jl   = lane & 31;
  const int half = lane >> 5;    // i-half: i in [half*64, half*64+64)
  const int j    = wid * 32 + jl;

  __shared__ __align__(16) h2    u_lds[2][80];   // h2 slots 0..31 and 36..67
  __shared__ __align__(16) float red[2][4];      // parity-buffered wave maxes
  __shared__ __align__(16) float red_sum[4];
  __shared__ __align__(16) float sY_sh[4];
  __shared__ __align__(16) float boot[4];

  const int Lb = L[b];
  const float* Pb = P + (size_t)b * T_LEN * M_DIM;
  const int*   Yb = Y + b * T_LEN;

#define BARRIER_RELAXED() do { \
    asm volatile("s_waitcnt lgkmcnt(0)" ::: "memory"); \
    __builtin_amdgcn_s_barrier(); } while (0)

  // W pairs: wpk[k*4+e] = f16{exp(A[i][j]), exp(A[i+1][j])}, i = 2*(half*32+k*4+e)
  h2 wpk[32];
  #pragma unroll
  for (int k = 0; k < 8; ++k) {
    #pragma unroll
    for (int e = 0; e < 4; ++e) {
      const int i = (half * 32 + k * 4 + e) * 2;
      h2 hv;
      hv.x = (_Float16)__expf(A[i * M_DIM + j]);
      hv.y = (_Float16)__expf(A[(i + 1) * M_DIM + j]);
      wpk[k * 4 + e] = hv;
    }
  }

  // Writer slot for u pairs (even-jl half0 lanes write pair m = j>>1).
  const int wslot_m = wid * 16 + (jl >> 1);
  const int wslot   = wslot_m < 32 ? wslot_m : 36 + (wslot_m - 32);
  const bool writer = (half == 0) && !(jl & 1);

  // ---- path score sY: no sequential dependency, gather in parallel ----
  float mySY = 0.f;
  for (int tt = tid; tt < Lb; tt += 256) {
    int yt = Yb[tt];
    float term = Pb[tt * M_DIM + yt];
    term += (tt == 0) ? A[M_DIM * M_DIM + yt] : A[Yb[tt - 1] * M_DIM + yt];
    mySY += term;
  }
  #pragma unroll
  for (int d = 1; d < 64; d <<= 1) mySY += __shfl_xor(mySY, d);
  if (lane == 0) sY_sh[wid] = mySY;

  // ---- t = 0 bootstrap: m0-normalize (stored max = 1.0) ----
  float s0 = Pb[j] + A[M_DIM * M_DIM + j];
  {
    float mm = s0;
    #pragma unroll
    for (int d = 1; d <= 16; d <<= 1) mm = fmaxf(mm, __shfl_xor(mm, d));
    if (lane == 0) boot[wid] = mm;
  }
  if (tid < 4) red[1][tid] = 1.0f;   // Z for step 1: max un_0 = 1 exactly
  __syncthreads();
  float C = fmaxf(fmaxf(boot[0], boot[1]), fmaxf(boot[2], boot[3]));  // m0
  float un = __expf(s0 - C);
  {
    float nb = __shfl_xor(un, 1);
    if (writer) {
      h2 hv; hv.x = (_Float16)un; hv.y = (_Float16)nb;
      u_lds[0][wslot] = hv;
    }
  }
  float p_cur = Pb[M_DIM + j];                   // row t=1 (always valid)
  if (Lb == 1) {
    float zs = un;
    #pragma unroll
    for (int d = 1; d <= 16; d <<= 1) zs += __shfl_xor(zs, d);
    if (lane == 0) red_sum[wid] = zs;
  }
  __syncthreads();
  if (Lb == 1) goto finish;

// Sub-step. PAR = t&1 (compile-time): read red[PAR], write red[PAR^1] with
// the max over THIS step's un (lag-1; lag-2 is unstable).
#define CRF_STEP(S, PAR, PNEXT)                                            \
  {                                                                        \
    const float4* u4 = (const float4*)(u_lds[cur]);                        \
    float4 rz = *(const float4*)(&red[PAR][0]);                            \
    float Z  = fmaxf(fmaxf(rz.x, rz.y), fmaxf(rz.z, rz.w));                \
    float ep = __expf(p_cur) * __builtin_amdgcn_rcpf(Z) * 0.00390625f;     \
    C += __logf(Z) + 5.54517744f;   /* log Z + 8 ln 2 */                   \
    float acc0 = 0.f, acc1 = 0.f, acc2 = 0.f, acc3 = 0.f;                  \
    _Pragma("unroll")                                                      \
    for (int k = 0; k < 8; ++k) {                                          \
      float4 uu = u4[half * 9 + k];                                        \
      acc0 = DOT2(__builtin_bit_cast(h2, uu.x), wpk[k * 4 + 0], acc0);     \
      acc1 = DOT2(__builtin_bit_cast(h2, uu.y), wpk[k * 4 + 1], acc1);     \
      acc2 = DOT2(__builtin_bit_cast(h2, uu.z), wpk[k * 4 + 2], acc2);     \
      acc3 = DOT2(__builtin_bit_cast(h2, uu.w), wpk[k * 4 + 3], acc3);     \
    }                                                                      \
    float v = (acc0 + acc1) + (acc2 + acc3);                               \
    v += __shfl_xor(v, 32);                                                \
    un = v * ep;                                                           \
    {                                                                      \
      float nb = __shfl_xor(un, 1);                                        \
      if (writer) {                                                        \
        h2 hv; hv.x = (_Float16)un; hv.y = (_Float16)nb;                   \
        u_lds[cur ^ 1][wslot] = hv;                                        \
      }                                                                    \
    }                                                                      \
    { /* lag-1 Z-tree over un_t, all-DPP (VALU pipe) */                    \
      float zm = un;                                                       \
      zm = fmaxf(zm, dppmov<0xB1>(zm));    /* xor1 */                      \
      zm = fmaxf(zm, dppmov<0x4E>(zm));    /* xor2 */                      \
      zm = fmaxf(zm, dppmov<0x141>(zm));   /* half-mirror == xor4 */       \
      zm = fmaxf(zm, dppmov<0x140>(zm));   /* mirror == xor8 */            \
      zm = fmaxf(zm, dppmov<0x142>(zm));   /* bcast15: 16..31 get row0 */  \
      if (lane == 16) red[(PAR) ^ 1][wid] = zm;                            \
    }                                                                      \
    const bool last_ = (tb + (S) == Lb - 1);                               \
    if (last_) {                                                           \
      float zs = un;                                                       \
      _Pragma("unroll")                                                    \
      for (int d = 1; d <= 16; d <<= 1) zs += __shfl_xor(zs, d);           \
      if (lane == 0) red_sum[wid] = zs;                                    \
    }                                                                      \
    BARRIER_RELAXED();                                                     \
    if (last_) goto finish;                                                \
    p_cur = (PNEXT);                                                       \
    cur ^= 1;                                                              \
  }

  {
    int cur = 0;
    int tb  = 1;   // iteration handles steps tb..tb+7; tb stays odd
    for (;;) {
      // Burst-prefetch P rows tb+1..tb+8 (clamped) into static regs.
      float pn0, pn1, pn2, pn3, pn4, pn5, pn6, pn7;
      {
        const float* Pq = Pb + j;
        int r;
        r = tb + 1; r = r < T_LEN ? r : T_LEN - 1; pn0 = Pq[r * M_DIM];
        r = tb + 2; r = r < T_LEN ? r : T_LEN - 1; pn1 = Pq[r * M_DIM];
        r = tb + 3; r = r < T_LEN ? r : T_LEN - 1; pn2 = Pq[r * M_DIM];
        r = tb + 4; r = r < T_LEN ? r : T_LEN - 1; pn3 = Pq[r * M_DIM];
        r = tb + 5; r = r < T_LEN ? r : T_LEN - 1; pn4 = Pq[r * M_DIM];
        r = tb + 6; r = r < T_LEN ? r : T_LEN - 1; pn5 = Pq[r * M_DIM];
        r = tb + 7; r = r < T_LEN ? r : T_LEN - 1; pn6 = Pq[r * M_DIM];
        r = tb + 8; r = r < T_LEN ? r : T_LEN - 1; pn7 = Pq[r * M_DIM];
      }
      // t = tb+S: odd for even S (tb odd) -> PAR = 1,0,1,0,...
      CRF_STEP(0, 1, pn0)
      CRF_STEP(1, 0, pn1)
      CRF_STEP(2, 1, pn2)
      CRF_STEP(3, 0, pn3)
      CRF_STEP(4, 1, pn4)
      CRF_STEP(5, 0, pn5)
      CRF_STEP(6, 1, pn6)
      CRF_STEP(7, 0, pn7)
      tb += 8;
    }
  }

finish:
  if (tid == 0) {
    float s  = (red_sum[0] + red_sum[1]) + (red_sum[2] + red_sum[3]);
    float sy = (sY_sh[0] + sY_sh[1]) + (sY_sh[2] + sY_sh[3]);
    out[b] = __logf(s) + C - sy;
  }
}

extern "C" void kernel_launch(void* const* d_in, const int* in_sizes, int n_in,
                              void* d_out, int out_size, void* d_ws, size_t ws_size,
                              hipStream_t stream) {
  const float* P = (const float*)d_in[0];
  const float* A = (const float*)d_in[1];
  const int*   Y = (const int*)d_in[2];
  const int*   L = (const int*)d_in[3];
  float* o = (float*)d_out;
  hipLaunchKernelGGL(crf_fwd, dim3(B_NUM), dim3(256), 0, stream, P, A, Y, L, o);
}